// Round 1
// baseline (240.522 us; speedup 1.0000x reference)
//
#include <hip/hip_runtime.h>
#include <math.h>

// CriticGraphPolicy fused kernel, MI355X (gfx950).
// B=65536, SD=32, AD=1, M=32. Dead code removed: m_up=0, m_td=0, msg-MLP unused.
// Structure: phase0 feature MLP (f32 VALU) -> per q-net fused K-pipeline:
//   layer1 (K=64 padded, bias folded as feature f39=1) -> relu -> bf16 h1 tile ->
//   layer2 (K=400 pad 416, N=300 pad 320) accumulated in MFMA regs ->
//   layer3 (N=1) fused epilogue reduction.

#define TBROWS 128
#define NTHR   512
#define BTOT   65536

typedef float  f32x4 __attribute__((ext_vector_type(4)));
typedef __bf16 bf16x8 __attribute__((ext_vector_type(8)));
typedef unsigned short u16x8 __attribute__((ext_vector_type(8)));
typedef unsigned short u16x4 __attribute__((ext_vector_type(4)));

struct Params {
  const float* state; const float* action;
  const float* f1w; const float* f1b;
  const float* f2w; const float* f2b;
  const float* f3w; const float* f3b;
  const float* qp[12];   // q1: w1,b1,w2,b2,w3,b3 ; q2: same
  float* out;
};

__device__ __forceinline__ unsigned short f2b(float f) {
  union { float f; unsigned int u; } v; v.f = f;
  return (unsigned short)((v.u + 0x7fffu + ((v.u >> 16) & 1u)) >> 16);
}
__device__ __forceinline__ float b2f(unsigned short u) {
  union { unsigned int u; float f; } v; v.u = ((unsigned int)u) << 16;
  return v.f;
}
__device__ __forceinline__ f32x4 MFMA(bf16x8 a, bf16x8 b, f32x4 c) {
  return __builtin_amdgcn_mfma_f32_16x16x32_bf16(a, b, c, 0, 0, 0);
}
__device__ __forceinline__ bf16x8 lds8(const unsigned short* p) {
  return __builtin_bit_cast(bf16x8, *(const u16x8*)p);
}

__global__ __launch_bounds__(NTHR, 2) void critic_fused_kernel(Params P) {
  // LDS: 55,808 B total (static, <64KB)
  __shared__ unsigned short xumA[TBROWS * 72];   // 18432 B  [row][k<64, pad 72] bf16, K=64 padded xum
  __shared__ unsigned short regA[4 * 320 * 8];   // 20480 B  w2 tile [kchunk][col][koff]; phase0 feat [row][72] (9216B)
  __shared__ unsigned short w1c [32 * 72];       //  4608 B  w1 cols [col<32][k<64, pad 72]
  __shared__ unsigned short h1t [TBROWS * 40];   // 10240 B  h1 tile [row][32 cols, pad 40] bf16
  __shared__ float          xred[TBROWS * 4];    //  2048 B  cross-wave row partials

  const int t   = threadIdx.x;
  const int row = t >> 2, sub = t & 3;      // 4 threads per batch row in phase 0
  const long grow = (long)blockIdx.x * TBROWS + row;

  // ---------------- phase 0: feature MLP (f32 VALU) ----------------
  float sa[33];
  {
    const float4* sp = (const float4*)(P.state + grow * 32);
    #pragma unroll
    for (int c = 0; c < 8; ++c) {
      float4 v = sp[c];
      sa[c*4+0] = v.x; sa[c*4+1] = v.y; sa[c*4+2] = v.z; sa[c*4+3] = v.w;
    }
    sa[32] = P.action[grow];
  }
  const int j0 = sub * 16;
  float acc[16];
  // fc1: xu = l2norm(sa @ w1 + b1); h = tanh(xu)
  #pragma unroll
  for (int j = 0; j < 16; ++j) acc[j] = P.f1b[j0 + j];
  #pragma unroll
  for (int i = 0; i < 33; ++i) {
    const float s = sa[i];
    const float4* wr = (const float4*)(P.f1w + i * 64 + j0);
    #pragma unroll
    for (int c = 0; c < 4; ++c) {
      float4 wv = wr[c];
      acc[c*4+0] += s * wv.x; acc[c*4+1] += s * wv.y;
      acc[c*4+2] += s * wv.z; acc[c*4+3] += s * wv.w;
    }
  }
  {
    float ss = 0.f;
    #pragma unroll
    for (int j = 0; j < 16; ++j) ss += acc[j] * acc[j];
    ss += __shfl_xor(ss, 1, 64); ss += __shfl_xor(ss, 2, 64);
    const float sc = 1.f / fmaxf(sqrtf(ss), 1e-12f);
    #pragma unroll
    for (int j = 0; j < 16; ++j) regA[row * 72 + j0 + j] = f2b(tanhf(acc[j] * sc));
  }
  __syncthreads();
  // fc2: h2 = tanh(h @ w2[0:64] + b2)   (rows 64..95 multiply tanh(0)=0)
  #pragma unroll
  for (int j = 0; j < 16; ++j) acc[j] = P.f2b[j0 + j];
  for (int i = 0; i < 64; ++i) {
    const float hv = b2f(regA[row * 72 + i]);
    const float4* wr = (const float4*)(P.f2w + i * 64 + j0);
    #pragma unroll
    for (int c = 0; c < 4; ++c) {
      float4 wv = wr[c];
      acc[c*4+0] += hv * wv.x; acc[c*4+1] += hv * wv.y;
      acc[c*4+2] += hv * wv.z; acc[c*4+3] += hv * wv.w;
    }
  }
  __syncthreads();
  #pragma unroll
  for (int j = 0; j < 16; ++j) regA[row * 72 + j0 + j] = f2b(tanhf(acc[j]));
  __syncthreads();
  // fc3: msg_up = l2norm(h2 @ w3 + b3)
  const int j0m = sub * 8;
  float am[8];
  #pragma unroll
  for (int j = 0; j < 8; ++j) am[j] = P.f3b[j0m + j];
  for (int i = 0; i < 64; ++i) {
    const float hv = b2f(regA[row * 72 + i]);
    const float4* wr = (const float4*)(P.f3w + i * 32 + j0m);
    #pragma unroll
    for (int c = 0; c < 2; ++c) {
      float4 wv = wr[c];
      am[c*4+0] += hv * wv.x; am[c*4+1] += hv * wv.y;
      am[c*4+2] += hv * wv.z; am[c*4+3] += hv * wv.w;
    }
  }
  float sm = 0.f;
  #pragma unroll
  for (int j = 0; j < 8; ++j) sm += am[j] * am[j];
  sm += __shfl_xor(sm, 1, 64); sm += __shfl_xor(sm, 2, 64);
  const float scm = 1.f / fmaxf(sqrtf(sm), 1e-12f);

  // xum features, K padded to 64:
  // f0..2=pos, f3..5=pos, f6..37=msg_up, f38=action, f39=1.0 (bias), f40..63=0
  #pragma unroll
  for (int k = 0; k < 16; ++k) xumA[row * 72 + j0 + k] = 0;
  __syncthreads();
  if (sub == 0) {
    #pragma unroll
    for (int c = 0; c < 3; ++c) {
      unsigned short pb = f2b(sa[c]);
      xumA[row * 72 + c] = pb;
      xumA[row * 72 + 3 + c] = pb;
    }
    xumA[row * 72 + 38] = f2b(sa[32]);
    xumA[row * 72 + 39] = 0x3f80; // 1.0
  }
  #pragma unroll
  for (int j = 0; j < 8; ++j) xumA[row * 72 + 6 + j0m + j] = f2b(am[j] * scm);
  __syncthreads();

  // ---------------- MFMA phases ----------------
  const int lane = t & 63, w = t >> 6;     // 8 waves
  const int rl = lane & 15, g = lane >> 4;
  // layer1 A-fragments (per wave: rows 16w..16w+15), same for both q-nets
  bf16x8 af0 = lds8(&xumA[(w * 16 + rl) * 72 + g * 8]);
  bf16x8 af1 = lds8(&xumA[(w * 16 + rl) * 72 + 32 + g * 8]);
  const int wm = w >> 2, wn = w & 3;       // layer2: 2 M-halves x 4 N-quarters

  for (int qi = 0; qi < 2; ++qi) {
    const float* w1  = P.qp[qi * 6 + 0];
    const float* b1  = P.qp[qi * 6 + 1];
    const float* w2  = P.qp[qi * 6 + 2];
    const float* b2p = P.qp[qi * 6 + 3];
    const float* w3  = P.qp[qi * 6 + 4];
    const float* b3  = P.qp[qi * 6 + 5];

    f32x4 acc2[4][5];
    #pragma unroll
    for (int mt = 0; mt < 4; ++mt)
      #pragma unroll
      for (int jn = 0; jn < 5; ++jn) acc2[mt][jn] = (f32x4){0.f, 0.f, 0.f, 0.f};

    for (int kt = 0; kt < 13; ++kt) {
      // stage 32 cols of W1eff: [col][k<64]; row k<39 -> w1[6+k], k==39 -> b1, else 0
      #pragma unroll
      for (int r = 0; r < 4; ++r) {
        int idx = t + r * NTHR;
        int cc = idx & 31, kk = idx >> 5;
        int cg = kt * 32 + cc;
        float v = 0.f;
        if (cg < 400) {
          if (kk < 39) v = w1[(6 + kk) * 400 + cg];
          else if (kk == 39) v = b1[cg];
        }
        w1c[cc * 72 + kk] = f2b(v);
      }
      // stage W2^T tile, blocked layout [kchunk(4)][col(320)][koff(8)]
      #pragma unroll
      for (int r = 0; r < 5; ++r) {
        int idx = t + r * NTHR;                 // < 2560
        int kq = idx / 320, n = idx - kq * 320; // kq<8 (quad of k), col n<320
        u16x4 pk = (u16x4){0, 0, 0, 0};
        #pragma unroll
        for (int c = 0; c < 4; ++c) {
          int kg = kt * 32 + kq * 4 + c;
          float v = (kg < 400 && n < 300) ? w2[kg * 300 + n] : 0.f;
          pk[c] = f2b(v);
        }
        *(u16x4*)&regA[(kq >> 1) * 2560 + n * 8 + 4 * (kq & 1)] = pk;
      }
      __syncthreads();

      // layer1: wave w -> its 16 rows, 32 output cols (= layer2 k-slice)
      f32x4 a1[2];
      a1[0] = (f32x4){0.f, 0.f, 0.f, 0.f};
      a1[1] = (f32x4){0.f, 0.f, 0.f, 0.f};
      #pragma unroll
      for (int nt = 0; nt < 2; ++nt) {
        bf16x8 bf_0 = lds8(&w1c[(nt * 16 + rl) * 72 + g * 8]);
        a1[nt] = MFMA(af0, bf_0, a1[nt]);
        bf16x8 bf_1 = lds8(&w1c[(nt * 16 + rl) * 72 + 32 + g * 8]);
        a1[nt] = MFMA(af1, bf_1, a1[nt]);
      }
      // relu -> bf16 h1 tile (bias already folded via f39)
      #pragma unroll
      for (int nt = 0; nt < 2; ++nt)
        #pragma unroll
        for (int i = 0; i < 4; ++i)
          h1t[(w * 16 + g * 4 + i) * 40 + nt * 16 + rl] = f2b(fmaxf(a1[nt][i], 0.f));
      __syncthreads();

      // layer2: wave (wm,wn): rows 64wm..+63 (4 M-tiles) x cols 80wn..+79 (5 N-tiles)
      bf16x8 a2f[4], bff[5];
      #pragma unroll
      for (int mt = 0; mt < 4; ++mt)
        a2f[mt] = lds8(&h1t[(wm * 64 + mt * 16 + rl) * 40 + g * 8]);
      #pragma unroll
      for (int jn = 0; jn < 5; ++jn)
        bff[jn] = lds8(&regA[g * 2560 + (wn * 80 + jn * 16 + rl) * 8]);
      #pragma unroll
      for (int mt = 0; mt < 4; ++mt)
        #pragma unroll
        for (int jn = 0; jn < 5; ++jn)
          acc2[mt][jn] = MFMA(a2f[mt], bff[jn], acc2[mt][jn]);
      __syncthreads();
    }

    // epilogue: x = sum_n relu(h2_n + b2_n) * w3_n + b3
    float xp[4][4];
    #pragma unroll
    for (int mt = 0; mt < 4; ++mt)
      #pragma unroll
      for (int i = 0; i < 4; ++i) xp[mt][i] = 0.f;
    #pragma unroll
    for (int jn = 0; jn < 5; ++jn) {
      int n = wn * 80 + jn * 16 + rl;
      if (n < 300) {
        float bv = b2p[n], wv = w3[n];
        #pragma unroll
        for (int mt = 0; mt < 4; ++mt)
          #pragma unroll
          for (int i = 0; i < 4; ++i)
            xp[mt][i] += fmaxf(acc2[mt][jn][i] + bv, 0.f) * wv;
      }
    }
    #pragma unroll
    for (int off = 1; off < 16; off <<= 1)
      #pragma unroll
      for (int mt = 0; mt < 4; ++mt)
        #pragma unroll
        for (int i = 0; i < 4; ++i)
          xp[mt][i] += __shfl_xor(xp[mt][i], off, 64);
    if (rl == 0) {
      #pragma unroll
      for (int mt = 0; mt < 4; ++mt)
        #pragma unroll
        for (int i = 0; i < 4; ++i)
          xred[(wm * 64 + mt * 16 + g * 4 + i) * 4 + wn] = xp[mt][i];
    }
    __syncthreads();
    if (t < TBROWS) {
      const float4 xv = *(const float4*)&xred[t * 4];
      P.out[(size_t)qi * BTOT + (size_t)blockIdx.x * TBROWS + t] =
          xv.x + xv.y + xv.z + xv.w + b3[0];
    }
    __syncthreads();
  }
}

extern "C" void kernel_launch(void* const* d_in, const int* in_sizes, int n_in,
                              void* d_out, int out_size, void* d_ws, size_t ws_size,
                              hipStream_t stream) {
  (void)in_sizes; (void)n_in; (void)out_size; (void)d_ws; (void)ws_size;
  Params P;
  P.state  = (const float*)d_in[0];
  P.action = (const float*)d_in[1];
  P.f1w = (const float*)d_in[2]; P.f1b = (const float*)d_in[3];
  P.f2w = (const float*)d_in[4]; P.f2b = (const float*)d_in[5];
  P.f3w = (const float*)d_in[6]; P.f3b = (const float*)d_in[7];
  // d_in[8..9] = att_w, att_b (mathematically dead: multiplied by zeros)
  for (int i = 0; i < 12; ++i) P.qp[i] = (const float*)d_in[10 + i];
  P.out = (float*)d_out;
  critic_fused_kernel<<<dim3(BTOT / TBROWS), dim3(NTHR), 0, stream>>>(P);
}

// Round 2
// 194.780 us; speedup vs baseline: 1.2348x; 1.2348x over previous
//
#include <hip/hip_runtime.h>
#include <math.h>

// CriticGraphPolicy fused kernel, MI355X (gfx950). Round 2.
// Dead code removed: m_up=0, m_td=0, msg-MLP unused.
// R2: weights pre-packed to bf16 LDS-layout images in d_ws (pack_weights),
// staged via global_load_lds dwordx4, double-buffered 26-tile pipeline with
// raw s_barrier + counted waitcnts (no __syncthreads in k-loop).

#define TBROWS 128
#define NTHR   512
#define BTOT   65536
#define NBLK   (BTOT / TBROWS)
#define TILE_B 25600            // bytes per packed weight tile (w2 20480 + w1 4608 + pad 512)
#define W2_B   20480
#define NTILE  26               // 2 q-nets x 13 k-tiles

typedef float  f32x4 __attribute__((ext_vector_type(4)));
typedef __bf16 bf16x8 __attribute__((ext_vector_type(8)));
typedef unsigned short u16x8 __attribute__((ext_vector_type(8)));

struct Params {
  const float* state; const float* action;
  const float* f1w; const float* f1b;
  const float* f2w; const float* f2b;
  const float* f3w; const float* f3b;
  const float* qp[12];          // q1: w1,b1,w2,b2,w3,b3 ; q2: same
  const unsigned char* img;     // packed bf16 weight images (d_ws)
  float* out;
};

struct PackP {
  const float* qp[12];
  unsigned short* ws;
};

__device__ __forceinline__ unsigned short f2b(float f) {
  union { float f; unsigned int u; } v; v.f = f;
  return (unsigned short)((v.u + 0x7fffu + ((v.u >> 16) & 1u)) >> 16);
}
__device__ __forceinline__ float b2f(unsigned short u) {
  union { unsigned int u; float f; } v; v.u = ((unsigned int)u) << 16;
  return v.f;
}
__device__ __forceinline__ f32x4 MFMA(bf16x8 a, bf16x8 b, f32x4 c) {
  return __builtin_amdgcn_mfma_f32_16x16x32_bf16(a, b, c, 0, 0, 0);
}
__device__ __forceinline__ bf16x8 lds8(const unsigned short* p) {
  return __builtin_bit_cast(bf16x8, *(const u16x8*)p);
}
__device__ __forceinline__ void gl_lds16(const void* g, void* l) {
  __builtin_amdgcn_global_load_lds(
      (__attribute__((address_space(1))) void*)(unsigned long long)(const char*)g,
      (__attribute__((address_space(3))) void*)(unsigned long long)(char*)l,
      16, 0, 0);
}

// ---------------- weight pack kernel ----------------
// image tile (q,kt) at (q*13+kt)*25600 bytes:
//   [0..20480):   w2 as [kc 4][col 320][koff 8] bf16  (kg=kt*32+kc*8+koff; zero-pad kg>=400, col>=300)
//   [20480..25088): w1eff as [col 32][k 72] bf16      (k<39: w1[6+k][cg], k==39: b1[cg], else 0)
//   [25088..25600): zero pad
__global__ void pack_weights(PackP P) {
  const int b = blockIdx.x, tid = threadIdx.x;
  if (b < 65) {                       // w2 part: 26 tiles * 4 kc * 320 col = 33280 threads
    int idx = b * 512 + tid;
    int col = idx % 320; int r = idx / 320;
    int kc = r & 3, tile = r >> 2;
    int q = tile / 13, kt = tile % 13;
    const float* w2 = P.qp[q * 6 + 2];
    unsigned short vals[8];
    #pragma unroll
    for (int koff = 0; koff < 8; ++koff) {
      int kg = kt * 32 + kc * 8 + koff;
      float v = (kg < 400 && col < 300) ? w2[kg * 300 + col] : 0.f;
      vals[koff] = f2b(v);
    }
    *(u16x8*)(P.ws + (size_t)tile * 12800 + (size_t)(kc * 320 + col) * 8) = *(const u16x8*)vals;
  } else {                            // w1+pad part: 26 tiles * 2560 elems = 66560 threads
    int idx = (b - 65) * 512 + tid;
    int e = idx % 2560, tile = idx / 2560;
    int q = tile / 13, kt = tile % 13;
    unsigned short v = 0;
    if (e < 2304) {
      int col = e / 72, k = e % 72;
      int cg = kt * 32 + col;
      if (cg < 400) {
        if (k < 39) v = f2b(P.qp[q * 6 + 0][(6 + k) * 400 + cg]);
        else if (k == 39) v = f2b(P.qp[q * 6 + 1][cg]);
      }
    }
    P.ws[(size_t)tile * 12800 + 10240 + e] = v;
  }
}

// ---------------- main fused kernel ----------------
__global__ __launch_bounds__(NTHR, 4) void critic_fused_kernel(Params P) {
  // LDS map (63488 B):
  //  [0..25600)       buf0 (weight tile dbuf slot 0)
  //  [25600..51200)   buf1; aliased: phase0 scratch hp [128][68] u16, then xumA [128][72] u16
  //  [51200..61440)   h1t [128][40] u16
  //  [61440..63488)   xred [128][4] f32
  __shared__ __align__(16) unsigned char smem[63488];
  unsigned char* buf0 = smem;
  unsigned char* buf1 = smem + TILE_B;
  unsigned short* hp   = (unsigned short*)(smem + TILE_B);
  unsigned short* xumA = (unsigned short*)(smem + TILE_B);
  unsigned short* h1t  = (unsigned short*)(smem + 2 * TILE_B);
  float*          xred = (float*)(smem + 2 * TILE_B + 10240);

  const int tid  = threadIdx.x;
  const int lane = tid & 63, w = tid >> 6;
  const int rl = lane & 15, g = lane >> 4;
  const int row = tid >> 2, sub = tid & 3;
  const long grow = (long)blockIdx.x * TBROWS + row;

  // prefetch weight tile 0 into buf0 (overlaps phase 0)
  {
    const unsigned char* img0 = P.img + lane * 16;
    #pragma unroll
    for (int i = 0; i < 3; ++i) gl_lds16(img0 + ((w + 8 * i) << 10), buf0 + ((w + 8 * i) << 10));
    if (w == 0) gl_lds16(img0 + (24 << 10), buf0 + (24 << 10));
  }

  // ---------------- phase 0: feature MLP (f32 VALU) ----------------
  float sa[33];
  {
    const float4* sp = (const float4*)(P.state + grow * 32);
    #pragma unroll
    for (int c = 0; c < 8; ++c) {
      float4 v = sp[c];
      sa[c*4+0] = v.x; sa[c*4+1] = v.y; sa[c*4+2] = v.z; sa[c*4+3] = v.w;
    }
    sa[32] = P.action[grow];
  }
  const int j0 = sub * 16;
  float acc[16];
  // fc1: h = tanh(l2norm(sa @ w1 + b1))
  #pragma unroll
  for (int j = 0; j < 16; ++j) acc[j] = P.f1b[j0 + j];
  #pragma unroll
  for (int i = 0; i < 33; ++i) {
    const float s = sa[i];
    const float4* wr = (const float4*)(P.f1w + i * 64 + j0);
    #pragma unroll
    for (int c = 0; c < 4; ++c) {
      float4 wv = wr[c];
      acc[c*4+0] += s * wv.x; acc[c*4+1] += s * wv.y;
      acc[c*4+2] += s * wv.z; acc[c*4+3] += s * wv.w;
    }
  }
  {
    float ss = 0.f;
    #pragma unroll
    for (int j = 0; j < 16; ++j) ss += acc[j] * acc[j];
    ss += __shfl_xor(ss, 1, 64); ss += __shfl_xor(ss, 2, 64);
    const float sc = 1.f / fmaxf(sqrtf(ss), 1e-12f);
    #pragma unroll
    for (int j = 0; j < 16; ++j) hp[row * 68 + j0 + j] = f2b(tanhf(acc[j] * sc));
  }
  __syncthreads();
  // fc2: h2 = tanh(h @ w2[0:64] + b2)
  #pragma unroll
  for (int j = 0; j < 16; ++j) acc[j] = P.f2b[j0 + j];
  for (int i = 0; i < 64; ++i) {
    const float hv = b2f(hp[row * 68 + i]);
    const float4* wr = (const float4*)(P.f2w + i * 64 + j0);
    #pragma unroll
    for (int c = 0; c < 4; ++c) {
      float4 wv = wr[c];
      acc[c*4+0] += hv * wv.x; acc[c*4+1] += hv * wv.y;
      acc[c*4+2] += hv * wv.z; acc[c*4+3] += hv * wv.w;
    }
  }
  __syncthreads();
  #pragma unroll
  for (int j = 0; j < 16; ++j) hp[row * 68 + j0 + j] = f2b(tanhf(acc[j]));
  __syncthreads();
  // fc3: msg_up = l2norm(h2 @ w3 + b3)
  const int j0m = sub * 8;
  float am[8];
  #pragma unroll
  for (int j = 0; j < 8; ++j) am[j] = P.f3b[j0m + j];
  for (int i = 0; i < 64; ++i) {
    const float hv = b2f(hp[row * 68 + i]);
    const float4* wr = (const float4*)(P.f3w + i * 32 + j0m);
    #pragma unroll
    for (int c = 0; c < 2; ++c) {
      float4 wv = wr[c];
      am[c*4+0] += hv * wv.x; am[c*4+1] += hv * wv.y;
      am[c*4+2] += hv * wv.z; am[c*4+3] += hv * wv.w;
    }
  }
  float sm = 0.f;
  #pragma unroll
  for (int j = 0; j < 8; ++j) sm += am[j] * am[j];
  sm += __shfl_xor(sm, 1, 64); sm += __shfl_xor(sm, 2, 64);
  const float scm = 1.f / fmaxf(sqrtf(sm), 1e-12f);
  __syncthreads();                    // hp dead; xumA aliases same bytes
  // xum features (K padded to 64): f0..2=pos, f3..5=pos, f6..37=msg, f38=action, f39=1
  #pragma unroll
  for (int k = 0; k < 16; ++k) xumA[row * 72 + j0 + k] = 0;
  __syncthreads();
  if (sub == 0) {
    #pragma unroll
    for (int c = 0; c < 3; ++c) {
      unsigned short pb = f2b(sa[c]);
      xumA[row * 72 + c] = pb;
      xumA[row * 72 + 3 + c] = pb;
    }
    xumA[row * 72 + 38] = f2b(sa[32]);
    xumA[row * 72 + 39] = 0x3f80;     // 1.0
  }
  #pragma unroll
  for (int j = 0; j < 8; ++j) xumA[row * 72 + 6 + j0m + j] = f2b(am[j] * scm);
  __syncthreads();                    // also drains vmcnt(0): tile 0 staged

  // layer1 A-fragments (rows 16w..16w+15), shared by both q-nets
  bf16x8 af0 = lds8(&xumA[(w * 16 + rl) * 72 + g * 8]);
  bf16x8 af1 = lds8(&xumA[(w * 16 + rl) * 72 + 32 + g * 8]);
  asm volatile("s_waitcnt lgkmcnt(0)" ::: "memory");
  __builtin_amdgcn_s_barrier();       // all waves hold frags; xumA region now free

  const int wm = w >> 2, wn = w & 3;  // layer2: 2 M-halves x 4 N-quarters
  f32x4 acc2[4][5];

  for (int tt = 0; tt < NTILE; ++tt) {
    const int kt = (tt < 13) ? tt : tt - 13;
    const int qx = (tt < 13) ? 0 : 1;
    unsigned char* bufc = (tt & 1) ? buf1 : buf0;
    if (kt == 0) {
      #pragma unroll
      for (int mt = 0; mt < 4; ++mt)
        #pragma unroll
        for (int jn = 0; jn < 5; ++jn) acc2[mt][jn] = (f32x4){0.f, 0.f, 0.f, 0.f};
    }
    // issue next tile's DMA (safe: barrier passed, prior readers of dst buf done)
    if (tt < NTILE - 1) {
      const unsigned char* img = P.img + (size_t)(tt + 1) * TILE_B + lane * 16;
      unsigned char* ldst = (tt & 1) ? buf0 : buf1;
      #pragma unroll
      for (int i = 0; i < 3; ++i) gl_lds16(img + ((w + 8 * i) << 10), ldst + ((w + 8 * i) << 10));
      if (w == 0) gl_lds16(img + (24 << 10), ldst + (24 << 10));
    }
    // layer1: wave w -> rows 16w..16w+15, 32 cols (this tile's k-slice)
    const unsigned short* w1c = (const unsigned short*)(bufc + W2_B);
    f32x4 a1[2];
    a1[0] = (f32x4){0.f, 0.f, 0.f, 0.f};
    a1[1] = (f32x4){0.f, 0.f, 0.f, 0.f};
    #pragma unroll
    for (int nt = 0; nt < 2; ++nt) {
      a1[nt] = MFMA(af0, lds8(&w1c[(nt * 16 + rl) * 72 + g * 8]), a1[nt]);
      a1[nt] = MFMA(af1, lds8(&w1c[(nt * 16 + rl) * 72 + 32 + g * 8]), a1[nt]);
    }
    #pragma unroll
    for (int nt = 0; nt < 2; ++nt)
      #pragma unroll
      for (int i = 0; i < 4; ++i)
        h1t[(w * 16 + g * 4 + i) * 40 + nt * 16 + rl] = f2b(fmaxf(a1[nt][i], 0.f));
    asm volatile("s_waitcnt lgkmcnt(0)" ::: "memory");
    __builtin_amdgcn_s_barrier();     // h1t ready; next-tile DMA stays in flight
    // layer2: wave (wm,wn): rows 64wm..+63 x cols 80wn..+79
    const unsigned short* w2l = (const unsigned short*)bufc;
    bf16x8 a2f[4];
    #pragma unroll
    for (int mt = 0; mt < 4; ++mt)
      a2f[mt] = lds8(&h1t[(wm * 64 + mt * 16 + rl) * 40 + g * 8]);
    #pragma unroll
    for (int jn = 0; jn < 5; ++jn) {
      bf16x8 bff = lds8(&w2l[g * 2560 + (wn * 80 + jn * 16 + rl) * 8]);
      #pragma unroll
      for (int mt = 0; mt < 4; ++mt)
        acc2[mt][jn] = MFMA(a2f[mt], bff, acc2[mt][jn]);
    }
    // epilogue after last k-tile of each q-net
    if (kt == 12) {
      const float* b2p = P.qp[qx * 6 + 3];
      const float* w3  = P.qp[qx * 6 + 4];
      const float* b3  = P.qp[qx * 6 + 5];
      float xp[4][4];
      #pragma unroll
      for (int mt = 0; mt < 4; ++mt)
        #pragma unroll
        for (int i = 0; i < 4; ++i) xp[mt][i] = 0.f;
      #pragma unroll
      for (int jn = 0; jn < 5; ++jn) {
        int n = wn * 80 + jn * 16 + rl;
        if (n < 300) {
          float bv = b2p[n], wv = w3[n];
          #pragma unroll
          for (int mt = 0; mt < 4; ++mt)
            #pragma unroll
            for (int i = 0; i < 4; ++i)
              xp[mt][i] += fmaxf(acc2[mt][jn][i] + bv, 0.f) * wv;
        }
      }
      #pragma unroll
      for (int off = 1; off < 16; off <<= 1)
        #pragma unroll
        for (int mt = 0; mt < 4; ++mt)
          #pragma unroll
          for (int i = 0; i < 4; ++i)
            xp[mt][i] += __shfl_xor(xp[mt][i], off, 64);
      if (rl == 0) {
        #pragma unroll
        for (int mt = 0; mt < 4; ++mt)
          #pragma unroll
          for (int i = 0; i < 4; ++i)
            xred[(wm * 64 + mt * 16 + g * 4 + i) * 4 + wn] = xp[mt][i];
      }
      asm volatile("s_waitcnt lgkmcnt(0)" ::: "memory");
      __builtin_amdgcn_s_barrier();
      if (tid < TBROWS) {
        const float4 xv = *(const float4*)&xred[tid * 4];
        P.out[(size_t)qx * BTOT + (size_t)blockIdx.x * TBROWS + tid] =
            xv.x + xv.y + xv.z + xv.w + b3[0];
      }
    }
    // iter end: own next-tile DMA complete, all waves done reading bufc
    if (tt < NTILE - 1) {
      asm volatile("s_waitcnt vmcnt(0)" ::: "memory");
      __builtin_amdgcn_s_barrier();
    }
  }
}

extern "C" void kernel_launch(void* const* d_in, const int* in_sizes, int n_in,
                              void* d_out, int out_size, void* d_ws, size_t ws_size,
                              hipStream_t stream) {
  (void)in_sizes; (void)n_in; (void)out_size; (void)ws_size;
  PackP K;
  for (int i = 0; i < 12; ++i) K.qp[i] = (const float*)d_in[10 + i];
  K.ws = (unsigned short*)d_ws;
  pack_weights<<<dim3(195), dim3(512), 0, stream>>>(K);

  Params P;
  P.state  = (const float*)d_in[0];
  P.action = (const float*)d_in[1];
  P.f1w = (const float*)d_in[2]; P.f1b = (const float*)d_in[3];
  P.f2w = (const float*)d_in[4]; P.f2b = (const float*)d_in[5];
  P.f3w = (const float*)d_in[6]; P.f3b = (const float*)d_in[7];
  for (int i = 0; i < 12; ++i) P.qp[i] = (const float*)d_in[10 + i];
  P.img = (const unsigned char*)d_ws;
  P.out = (float*)d_out;
  critic_fused_kernel<<<dim3(NBLK), dim3(NTHR), 0, stream>>>(P);
}